// Round 14
// baseline (544.258 us; speedup 1.0000x reference)
//
#include <hip/hip_runtime.h>
#include <hip/hip_bf16.h>

// GraphSAGE 2-layer + mean-pool + linear head, MI355X (gfx950).
// Dtypes (R0-R5 forensics): floats fp32, indices int32, out fp32.
// R6 CSR-gather 1243us | R7 MFMA 757 | R8 LDS-W 593 | R9 XCD-fill 537 |
// R10 fp8 tables 517 | R11 MLP gather 438 | R12 k_cnt 359 | R13 nt-fill 356.
// R14: k_fill col lines still bounced across XCDs (blockIdx&7 mapping was a
// guess). Now each block reads its REAL XCD via s_getreg(HW_REG_XCC_ID)
// (HW-verified on gfx950) and pulls edge-slices from a per-XCD work queue,
// processing bucket==xcc; falls back to stealing other buckets when its
// queue drains (correct under ANY xcc mapping; pinning is purely perf).
// Also fused xconv+wconv+cnt into one prep dispatch.

#define NN 100000
#define NE 1600000
#define DH 128
#define NG 512
#define CSTRIDE 48   // deg ~ Poisson(16); P(max>=48) ~ 5.6e-6, guarded anyway
#define NBKT 8
#define BKT_SZ 12500 // NN / NBKT
#define NSLICE 256
#define ESLICE 6250  // NE / NSLICE

#define PSUM_SCALE  1048576.0f        // 2^20
#define PSUM_INV    (1.0f/1048576.0f)

typedef __hip_bfloat16 bf16;
typedef __bf16 bf16x8 __attribute__((ext_vector_type(8)));
typedef float  f32x4  __attribute__((ext_vector_type(4)));
typedef float  f32x2  __attribute__((ext_vector_type(2)));
typedef unsigned char u8;

__device__ __forceinline__ void bf8_to_f(uint4 q, float* w) {
    union { unsigned u; float f; } t;
    t.u = q.x << 16;          w[0] = t.f;
    t.u = q.x & 0xffff0000u;  w[1] = t.f;
    t.u = q.y << 16;          w[2] = t.f;
    t.u = q.y & 0xffff0000u;  w[3] = t.f;
    t.u = q.z << 16;          w[4] = t.f;
    t.u = q.z & 0xffff0000u;  w[5] = t.f;
    t.u = q.w << 16;          w[6] = t.f;
    t.u = q.w & 0xffff0000u;  w[7] = t.f;
}

// pack 4 floats -> 4 fp8 e4m3 bytes (HW, RNE)
__device__ __forceinline__ unsigned pack4_fp8(float a, float b, float c, float d) {
    int p = __builtin_amdgcn_cvt_pk_fp8_f32(a, b, 0, false);
    p = __builtin_amdgcn_cvt_pk_fp8_f32(c, d, p, true);
    return (unsigned)p;
}

// ---------------------------------------------------------------- prep ----

// Fused: x->fp8 (all 6250 blocks), W->bf16 (blocks 0..255), cnt via binary
// search on sorted batch (blocks 256..257).
__global__ __launch_bounds__(256) void k_prep2(
    const float* __restrict__ x, u8* __restrict__ fq,
    const float* __restrict__ w0, const float* __restrict__ w1,
    const float* __restrict__ w2, const float* __restrict__ w3,
    bf16* __restrict__ wb,
    const int* __restrict__ batch, int* __restrict__ cnt)
{
    const int bid = blockIdx.x, tid = threadIdx.x;

    // xconv: 8 elems/thread
    {
        int g = bid * 256 + tid;                  // 0 .. 1599999
        const float4* s = (const float4*)(x + (size_t)g * 8);
        float4 u0 = s[0], u1 = s[1];
        uint2 v;
        v.x = pack4_fp8(u0.x, u0.y, u0.z, u0.w);
        v.y = pack4_fp8(u1.x, u1.y, u1.z, u1.w);
        *(uint2*)(fq + (size_t)g * 8) = v;
    }

    if (bid < 256) {                              // wconv
        int gid = bid * 256 + tid;                // 0 .. 65535
        int m = gid >> 14, i = gid & 16383;
        const float* src = (m == 0) ? w0 : (m == 1) ? w1 : (m == 2) ? w2 : w3;
        wb[gid] = __float2bfloat16(src[i]);
    } else if (bid < 258) {                       // cnt
        int g = (bid - 256) * 256 + tid;
        if (g < NG) {
            int lo0 = 0, hi0 = NN, lo1 = 0, hi1 = NN;
            while (lo0 < hi0) { int m = (lo0 + hi0) >> 1; if (batch[m] < g)     lo0 = m + 1; else hi0 = m; }
            while (lo1 < hi1) { int m = (lo1 + hi1) >> 1; if (batch[m] < g + 1) lo1 = m + 1; else hi1 = m; }
            cnt[g] = lo1 - lo0;
        }
    }
}

// XCC-pinned work-queue CSR fill. Block reads its real XCD id, drains that
// bucket's slice queue (col slice then lives in exactly one L2), then steals
// other buckets' remaining slices. Correct under any xcc mapping.
__global__ __launch_bounds__(256) void k_fill(
    const int* __restrict__ ei, int* __restrict__ deg, int* __restrict__ col,
    int* __restrict__ q)
{
    __shared__ int sl;
    unsigned xcc;
    asm volatile("s_getreg_b32 %0, hwreg(HW_REG_XCC_ID)" : "=s"(xcc));
    xcc &= (NBKT - 1);

    for (int a = 0; a < NBKT; ++a) {
        const int b = (xcc + a) & (NBKT - 1);
        const int lo = b * BKT_SZ, hi = lo + BKT_SZ;
        for (;;) {
            if (threadIdx.x == 0) sl = atomicAdd(&q[b], 1);
            __syncthreads();
            const int s0 = sl;
            __syncthreads();
            if (s0 >= NSLICE) break;
            const int e0 = s0 * ESLICE;
            for (int e = e0 + threadIdx.x; e < e0 + ESLICE; e += 256) {
                int d = __builtin_nontemporal_load(ei + NE + e);
                if (d >= lo && d < hi) {
                    int s = __builtin_nontemporal_load(ei + e);
                    int pos = atomicAdd(&deg[d], 1);
                    if (pos < CSTRIDE) col[d * CSTRIDE + pos] = s;
                }
            }
        }
    }
}

// -------------------------------------------------------------- gather ----

// Gather-mean from fp8 rows (128B). One wave per node. Quarter-wave owns an
// edge slot (qsub = lane>>4): lane loads 8B = 8 features of one row; one
// wave-load covers 4 random rows. Unroll x2 -> 8 rows in flight.
__global__ __launch_bounds__(256) void k_gather(
    const int* __restrict__ deg, const int* __restrict__ col,
    const u8* __restrict__ fq, bf16* __restrict__ agg)
{
    const int nid  = blockIdx.x * 4 + (threadIdx.x >> 6);
    const int lane = threadIdx.x & 63;
    const int qsub = lane >> 4;        // edge slot 0..3
    const int l4   = lane & 15;        // feature group: 8*l4 .. 8*l4+7
    int dgr = __builtin_amdgcn_readfirstlane(deg[nid]);
    int dg = dgr > CSTRIDE ? CSTRIDE : dgr;
    int vidx = (lane < CSTRIDE) ? col[nid * CSTRIDE + lane] : 0;

    float a[8] = {0.f, 0.f, 0.f, 0.f, 0.f, 0.f, 0.f, 0.f};

    for (int e = 0; e < dg; e += 8) {
        int sa0 = __builtin_amdgcn_readlane(vidx, min(e + 0, dg - 1));
        int sa1 = __builtin_amdgcn_readlane(vidx, min(e + 1, dg - 1));
        int sa2 = __builtin_amdgcn_readlane(vidx, min(e + 2, dg - 1));
        int sa3 = __builtin_amdgcn_readlane(vidx, min(e + 3, dg - 1));
        int sb0 = __builtin_amdgcn_readlane(vidx, min(e + 4, dg - 1));
        int sb1 = __builtin_amdgcn_readlane(vidx, min(e + 5, dg - 1));
        int sb2 = __builtin_amdgcn_readlane(vidx, min(e + 6, dg - 1));
        int sb3 = __builtin_amdgcn_readlane(vidx, min(e + 7, dg - 1));
        int sA = (qsub == 0) ? sa0 : (qsub == 1) ? sa1 : (qsub == 2) ? sa2 : sa3;
        int sB = (qsub == 0) ? sb0 : (qsub == 1) ? sb1 : (qsub == 2) ? sb2 : sb3;
        float mA = (e + qsub     < dg) ? 1.f : 0.f;
        float mB = (e + 4 + qsub < dg) ? 1.f : 0.f;
        uint2 qA = *(const uint2*)(fq + (size_t)sA * DH + l4 * 8);
        uint2 qB = *(const uint2*)(fq + (size_t)sB * DH + l4 * 8);
        f32x2 v0 = __builtin_amdgcn_cvt_pk_f32_fp8((int)qA.x, false);
        f32x2 v1 = __builtin_amdgcn_cvt_pk_f32_fp8((int)qA.x, true);
        f32x2 v2 = __builtin_amdgcn_cvt_pk_f32_fp8((int)qA.y, false);
        f32x2 v3 = __builtin_amdgcn_cvt_pk_f32_fp8((int)qA.y, true);
        a[0] += v0[0] * mA; a[1] += v0[1] * mA;
        a[2] += v1[0] * mA; a[3] += v1[1] * mA;
        a[4] += v2[0] * mA; a[5] += v2[1] * mA;
        a[6] += v3[0] * mA; a[7] += v3[1] * mA;
        v0 = __builtin_amdgcn_cvt_pk_f32_fp8((int)qB.x, false);
        v1 = __builtin_amdgcn_cvt_pk_f32_fp8((int)qB.x, true);
        v2 = __builtin_amdgcn_cvt_pk_f32_fp8((int)qB.y, false);
        v3 = __builtin_amdgcn_cvt_pk_f32_fp8((int)qB.y, true);
        a[0] += v0[0] * mB; a[1] += v0[1] * mB;
        a[2] += v1[0] * mB; a[3] += v1[1] * mB;
        a[4] += v2[0] * mB; a[5] += v2[1] * mB;
        a[6] += v3[0] * mB; a[7] += v3[1] * mB;
    }

    #pragma unroll
    for (int i = 0; i < 8; ++i) {
        a[i] += __shfl_xor(a[i], 16, 64);
        a[i] += __shfl_xor(a[i], 32, 64);
    }

    if (qsub == 0) {
        float di = 1.0f / fmaxf((float)dgr, 1.0f);
        union { bf16 b[8]; uint4 u; } pk;
        #pragma unroll
        for (int i = 0; i < 8; ++i) pk.b[i] = __float2bfloat16(a[i] * di);
        *(uint4*)(agg + nid * DH + l4 * 8) = pk.u;
    }
}

// --------------------------------------------------------- MFMA layer ----

#define WSTR 136   // LDS row stride (bf16): +8 pad -> 2-way conflict (free)

template <bool POOL>
__global__ __launch_bounds__(256, 4) void k_layer(
    const bf16* __restrict__ agg, const void* __restrict__ xop,
    const bf16* __restrict__ Wlb, const bf16* __restrict__ Wrb,
    const float* __restrict__ bias,
    u8* __restrict__ outq, int* __restrict__ psum,
    const int* __restrict__ batch)
{
    __shared__ bf16 wl[128 * WSTR];   // 34816 B, reused as output staging
    __shared__ int  bb[128];

    const int tid  = threadIdx.x;
    const int wave = tid >> 6;
    const int lane = tid & 63;
    const int lm   = lane & 15;
    const int kg   = lane >> 4;
    const int base = blockIdx.x * 128;
    const int wbase = base + wave * 32;

    const int r0 = min(wbase + lm,      NN - 1);
    const int r1 = min(wbase + 16 + lm, NN - 1);

    if (POOL && tid < 128) bb[tid] = batch[min(base + tid, NN - 1)];

    // stage Wl
    {
        const int row = tid >> 1, half = tid & 1;
        const uint4* src = (const uint4*)(Wlb + row * DH + half * 64);
        uint4* dst = (uint4*)(wl + row * WSTR + half * 64);
        #pragma unroll
        for (int i = 0; i < 8; ++i) dst[i] = src[i];
    }
    __syncthreads();

    f32x4 acc[2][8];
    #pragma unroll
    for (int i = 0; i < 2; ++i)
        #pragma unroll
        for (int t = 0; t < 8; ++t)
            acc[i][t] = (f32x4){0.f, 0.f, 0.f, 0.f};

    // ---- half 1: agg . Wl(LDS) ----
    #pragma unroll
    for (int kc = 0; kc < 4; ++kc) {
        const int ko = kc * 32 + kg * 8;
        bf16x8 a0 = *(const bf16x8*)(agg + r0 * DH + ko);
        bf16x8 a1 = *(const bf16x8*)(agg + r1 * DH + ko);
        #pragma unroll
        for (int t = 0; t < 8; ++t) {
            bf16x8 b = *(const bf16x8*)(wl + (t * 16 + lm) * WSTR + ko);
            acc[0][t] = __builtin_amdgcn_mfma_f32_16x16x32_bf16(a0, b, acc[0][t], 0, 0, 0);
            acc[1][t] = __builtin_amdgcn_mfma_f32_16x16x32_bf16(a1, b, acc[1][t], 0, 0, 0);
        }
    }
    __syncthreads();

    // restage Wr
    {
        const int row = tid >> 1, half = tid & 1;
        const uint4* src = (const uint4*)(Wrb + row * DH + half * 64);
        uint4* dst = (uint4*)(wl + row * WSTR + half * 64);
        #pragma unroll
        for (int i = 0; i < 8; ++i) dst[i] = src[i];
    }
    __syncthreads();

    // ---- half 2: x . Wr(LDS) ----
    #pragma unroll
    for (int kc = 0; kc < 4; ++kc) {
        const int ko = kc * 32 + kg * 8;
        bf16x8 a0, a1;
        if (!POOL) {
            const float* xf = (const float*)xop;
            const float4* p0 = (const float4*)(xf + (size_t)r0 * DH + ko);
            const float4* p1 = (const float4*)(xf + (size_t)r1 * DH + ko);
            float4 u0 = p0[0], u1 = p0[1], v0 = p1[0], v1 = p1[1];
            a0[0] = (__bf16)u0.x; a0[1] = (__bf16)u0.y; a0[2] = (__bf16)u0.z; a0[3] = (__bf16)u0.w;
            a0[4] = (__bf16)u1.x; a0[5] = (__bf16)u1.y; a0[6] = (__bf16)u1.z; a0[7] = (__bf16)u1.w;
            a1[0] = (__bf16)v0.x; a1[1] = (__bf16)v0.y; a1[2] = (__bf16)v0.z; a1[3] = (__bf16)v0.w;
            a1[4] = (__bf16)v1.x; a1[5] = (__bf16)v1.y; a1[6] = (__bf16)v1.z; a1[7] = (__bf16)v1.w;
        } else {
            const u8* xq = (const u8*)xop;
            uint2 q0 = *(const uint2*)(xq + (size_t)r0 * DH + ko);
            uint2 q1 = *(const uint2*)(xq + (size_t)r1 * DH + ko);
            f32x2 c0 = __builtin_amdgcn_cvt_pk_f32_fp8((int)q0.x, false);
            f32x2 c1 = __builtin_amdgcn_cvt_pk_f32_fp8((int)q0.x, true);
            f32x2 c2 = __builtin_amdgcn_cvt_pk_f32_fp8((int)q0.y, false);
            f32x2 c3 = __builtin_amdgcn_cvt_pk_f32_fp8((int)q0.y, true);
            a0[0] = (__bf16)c0[0]; a0[1] = (__bf16)c0[1];
            a0[2] = (__bf16)c1[0]; a0[3] = (__bf16)c1[1];
            a0[4] = (__bf16)c2[0]; a0[5] = (__bf16)c2[1];
            a0[6] = (__bf16)c3[0]; a0[7] = (__bf16)c3[1];
            c0 = __builtin_amdgcn_cvt_pk_f32_fp8((int)q1.x, false);
            c1 = __builtin_amdgcn_cvt_pk_f32_fp8((int)q1.x, true);
            c2 = __builtin_amdgcn_cvt_pk_f32_fp8((int)q1.y, false);
            c3 = __builtin_amdgcn_cvt_pk_f32_fp8((int)q1.y, true);
            a1[0] = (__bf16)c0[0]; a1[1] = (__bf16)c0[1];
            a1[2] = (__bf16)c1[0]; a1[3] = (__bf16)c1[1];
            a1[4] = (__bf16)c2[0]; a1[5] = (__bf16)c2[1];
            a1[6] = (__bf16)c3[0]; a1[7] = (__bf16)c3[1];
        }
        #pragma unroll
        for (int t = 0; t < 8; ++t) {
            bf16x8 b = *(const bf16x8*)(wl + (t * 16 + lm) * WSTR + ko);
            acc[0][t] = __builtin_amdgcn_mfma_f32_16x16x32_bf16(a0, b, acc[0][t], 0, 0, 0);
            acc[1][t] = __builtin_amdgcn_mfma_f32_16x16x32_bf16(a1, b, acc[1][t], 0, 0, 0);
        }
    }
    __syncthreads();   // all waves done reading wl -> safe to reuse

    // ---- epilogue: stage bias+relu'd outputs (bf16) row-major in LDS ----
    bf16* ob = wl;     // 128 x 128, stride 128 (32KB)
    const int quad = lane >> 4;
    #pragma unroll
    for (int i = 0; i < 2; ++i) {
        #pragma unroll
        for (int r = 0; r < 4; ++r) {
            const int lr = wave * 32 + i * 16 + quad * 4 + r;
            const int n  = base + lr;
            #pragma unroll
            for (int t = 0; t < 8; ++t) {
                const int f = t * 16 + lm;
                float v = fmaxf(acc[i][t][r] + bias[f], 0.f);
                if (POOL && n >= NN) v = 0.f;   // zero tail for pooling
                ob[lr * DH + f] = __float2bfloat16(v);
            }
        }
    }
    __syncthreads();

    if (!POOL) {
        // coalesced fp8 store: block tile is contiguous 16KB in outq
        uint2* d = (uint2*)(outq + (size_t)base * DH);
        #pragma unroll
        for (int i = 0; i < 8; ++i) {
            const int idx = i * 256 + tid;          // 8B units, 16 per row
            const int n = base + (idx >> 4);
            if (n < NN) {
                uint4 s = ((const uint4*)ob)[idx];  // 8 bf16
                float w[8];
                bf8_to_f(s, w);
                uint2 o;
                o.x = pack4_fp8(w[0], w[1], w[2], w[3]);
                o.y = pack4_fp8(w[4], w[5], w[6], w[7]);
                d[idx] = o;
            }
        }
    } else {
        // sorted-batch run-length pooling: thread = (col f, half h)
        const int f = tid & 127, h = tid >> 7;
        float rs = 0.f;
        int cur = bb[h * 64];
        #pragma unroll 8
        for (int r = 0; r < 64; ++r) {
            const int row = h * 64 + r;
            float v = __bfloat162float(ob[row * DH + f]);
            int b = bb[row];
            if (b != cur) {   // wave-uniform (depends only on row)
                atomicAdd(&psum[cur * DH + f], __float2int_rn(rs * PSUM_SCALE));
                rs = 0.f; cur = b;
            }
            rs += v;
        }
        atomicAdd(&psum[cur * DH + f], __float2int_rn(rs * PSUM_SCALE));
    }
}

// --------------------------------------------------------------- final ----

__global__ __launch_bounds__(256) void k_final(
    const int* __restrict__ psum, const int* __restrict__ cnt,
    const float* __restrict__ Wlin, const float* __restrict__ blin,
    float* __restrict__ out)
{
    int gid = blockIdx.x * 256 + threadIdx.x;
    if (gid >= NG * 4) return;
    int gph = gid >> 2, c = gid & 3;
    const int* p = psum + gph * DH;
    const float* w = Wlin + c * DH;
    float s = 0.f;
    #pragma unroll 8
    for (int k = 0; k < DH; ++k)
        s += (float)p[k] * w[k];
    float inv = 1.0f / fmaxf((float)cnt[gph], 1.0f);
    out[gid] = s * PSUM_INV * inv + blin[c];
}

extern "C" void kernel_launch(void* const* d_in, const int* in_sizes, int n_in,
                              void* d_out, int out_size, void* d_ws, size_t ws_size,
                              hipStream_t stream) {
    const float* x     = (const float*)d_in[0];
    const int*   ei    = (const int*)d_in[1];
    const int*   batch = (const int*)d_in[2];
    const float* W1l   = (const float*)d_in[3];
    const float* b1    = (const float*)d_in[4];
    const float* W1r   = (const float*)d_in[5];
    const float* W2l   = (const float*)d_in[6];
    const float* b2    = (const float*)d_in[7];
    const float* W2r   = (const float*)d_in[8];
    const float* Wlin  = (const float*)d_in[9];
    const float* blin  = (const float*)d_in[10];
    float* out = (float*)d_out;

    // ws layout (58.4MB, well under proven 77.46MB):
    // q:    8 int           @ 0           (32)       fill work queues
    // deg:  NN int          @ 64          (400000)
    // cnt:  512 int         @ 400064      (2048)
    // psum: 512*128 int     @ 402112      (262144)
    // wb:   4*16384 bf16    @ 664256      (131072)
    // col:  NN*48 int       @ 795328      (19200000)
    // agg:  NN*128 bf16     @ 19995328    (25600000)
    // fq:   NN*128 fp8      @ 45595328    (12800000)  xq, then h1q in-place
    char* base = (char*)d_ws;
    int*   q    = (int*)(base);
    int*   deg  = (int*)(base + 64);
    int*   cnt  = (int*)(base + 400064);
    int*   psum = (int*)(base + 402112);
    bf16*  wb   = (bf16*)(base + 664256);
    int*   col  = (int*)(base + 795328);
    bf16*  agg  = (bf16*)(base + 19995328);
    u8*    fq   = (u8*)(base + 45595328);

    bf16* W1lb = wb;
    bf16* W1rb = wb + 16384;
    bf16* W2lb = wb + 32768;
    bf16* W2rb = wb + 49152;

    // zero q + deg + psum (cnt written by prep2; rest fully overwritten)
    hipMemsetAsync(d_ws, 0, 664256, stream);

    k_prep2<<<6250, 256, 0, stream>>>(x, fq, W1l, W1r, W2l, W2r, wb, batch, cnt);
    k_fill<<<2048, 256, 0, stream>>>(ei, deg, col, q);

    // layer 1: gather xq(fp8) -> agg(bf16), MFMA GEMM -> h1q(fp8, over xq)
    k_gather<<<NN / 4, 256, 0, stream>>>(deg, col, fq, agg);
    k_layer<false><<<(NN + 127) / 128, 256, 0, stream>>>(agg, x, W1lb, W1rb, b1,
                                                         fq, nullptr, nullptr);

    // layer 2: gather h1q(fp8) -> agg(bf16), MFMA GEMM + pooling -> psum
    k_gather<<<NN / 4, 256, 0, stream>>>(deg, col, fq, agg);
    k_layer<true><<<(NN + 127) / 128, 256, 0, stream>>>(agg, fq, W2lb, W2rb, b2,
                                                        nullptr, psum, batch);

    k_final<<<8, 256, 0, stream>>>(psum, cnt, Wlin, blin, out);
}

// Round 15
// 344.885 us; speedup vs baseline: 1.5781x; 1.5781x over previous
//
#include <hip/hip_runtime.h>
#include <hip/hip_bf16.h>

// GraphSAGE 2-layer + mean-pool + linear head, MI355X (gfx950).
// Dtypes (R0-R5 forensics): floats fp32, indices int32, out fp32.
// R6 CSR-gather 1243us | R7 MFMA 757 | R8 LDS-W 593 | R9 XCD-fill 537 |
// R10 fp8 tables 517 | R11 MLP gather 438 | R12 k_cnt 359 | R13 nt-fill 356 |
// R14 work-queue fill REGRESSED (270us/dispatch: ~18K same-address queue
//     atomics + barrier-per-pop serialization; XCC pinning changed WRITE 0%
//     -> cross-XCD-bounce theory disconfirmed; residual WRITE is the deg
//     RMW floor + inherent partial-line col writes). REVERTED.
// R15: R13 fill restored verbatim; prep (xconv/wconv/cnt) fused into the
//     same dispatch as disjoint block ranges (independent work) to hide
//     ~15-20us of serial prep + 2 launch gaps behind the fill long pole.

#define NN 100000
#define NE 1600000
#define DH 128
#define NG 512
#define CSTRIDE 48   // deg ~ Poisson(16); P(max>=48) ~ 5.6e-6, guarded anyway
#define NBKT 8
#define BKT_SZ 12500 // NN / NBKT
#define NSLICE 256
#define ESLICE 6250  // NE / NSLICE
#define NFILL 2048   // fill blocks (NSLICE * NBKT)
#define NPREP 6250   // xconv blocks

#define PSUM_SCALE  1048576.0f        // 2^20
#define PSUM_INV    (1.0f/1048576.0f)

typedef __hip_bfloat16 bf16;
typedef __bf16 bf16x8 __attribute__((ext_vector_type(8)));
typedef float  f32x4  __attribute__((ext_vector_type(4)));
typedef float  f32x2  __attribute__((ext_vector_type(2)));
typedef unsigned char u8;

__device__ __forceinline__ void bf8_to_f(uint4 q, float* w) {
    union { unsigned u; float f; } t;
    t.u = q.x << 16;          w[0] = t.f;
    t.u = q.x & 0xffff0000u;  w[1] = t.f;
    t.u = q.y << 16;          w[2] = t.f;
    t.u = q.y & 0xffff0000u;  w[3] = t.f;
    t.u = q.z << 16;          w[4] = t.f;
    t.u = q.z & 0xffff0000u;  w[5] = t.f;
    t.u = q.w << 16;          w[6] = t.f;
    t.u = q.w & 0xffff0000u;  w[7] = t.f;
}

// pack 4 floats -> 4 fp8 e4m3 bytes (HW, RNE)
__device__ __forceinline__ unsigned pack4_fp8(float a, float b, float c, float d) {
    int p = __builtin_amdgcn_cvt_pk_fp8_f32(a, b, 0, false);
    p = __builtin_amdgcn_cvt_pk_fp8_f32(c, d, p, true);
    return (unsigned)p;
}

// ------------------------------------------------------ fused fill+prep ----

// Blocks 0..NFILL-1: R13's XCD-bucketed nt-load CSR fill (bucket=bid&7).
// Blocks NFILL..NFILL+NPREP-1: x->fp8; first 256 of them also W->bf16;
// next 2 also cnt via binary search. All ranges fully independent.
__global__ __launch_bounds__(256) void k_fill_prep(
    const int* __restrict__ ei, int* __restrict__ deg, int* __restrict__ col,
    const float* __restrict__ x, u8* __restrict__ fq,
    const float* __restrict__ w0, const float* __restrict__ w1,
    const float* __restrict__ w2, const float* __restrict__ w3,
    bf16* __restrict__ wb,
    const int* __restrict__ batch, int* __restrict__ cnt)
{
    const int bid = blockIdx.x, tid = threadIdx.x;

    if (bid < NFILL) {
        const int bucket = bid & (NBKT - 1);
        const int wi     = bid >> 3;
        const int lo = bucket * BKT_SZ, hi = lo + BKT_SZ;
        const int e0 = wi * ESLICE;
        for (int e = e0 + tid; e < e0 + ESLICE; e += 256) {
            int d = __builtin_nontemporal_load(ei + NE + e);
            if (d >= lo && d < hi) {
                int s = __builtin_nontemporal_load(ei + e);
                int pos = atomicAdd(&deg[d], 1);
                if (pos < CSTRIDE) col[d * CSTRIDE + pos] = s;
            }
        }
        return;
    }

    const int pb = bid - NFILL;                   // 0 .. NPREP-1
    {   // xconv: 8 elems/thread
        int g = pb * 256 + tid;                   // 0 .. 1599999
        const float4* s = (const float4*)(x + (size_t)g * 8);
        float4 u0 = s[0], u1 = s[1];
        uint2 v;
        v.x = pack4_fp8(u0.x, u0.y, u0.z, u0.w);
        v.y = pack4_fp8(u1.x, u1.y, u1.z, u1.w);
        *(uint2*)(fq + (size_t)g * 8) = v;
    }
    if (pb < 256) {                               // wconv
        int gid = pb * 256 + tid;                 // 0 .. 65535
        int m = gid >> 14, i = gid & 16383;
        const float* src = (m == 0) ? w0 : (m == 1) ? w1 : (m == 2) ? w2 : w3;
        wb[gid] = __float2bfloat16(src[i]);
    } else if (pb < 258) {                        // cnt (sorted batch)
        int g = (pb - 256) * 256 + tid;
        if (g < NG) {
            int lo0 = 0, hi0 = NN, lo1 = 0, hi1 = NN;
            while (lo0 < hi0) { int m = (lo0 + hi0) >> 1; if (batch[m] < g)     lo0 = m + 1; else hi0 = m; }
            while (lo1 < hi1) { int m = (lo1 + hi1) >> 1; if (batch[m] < g + 1) lo1 = m + 1; else hi1 = m; }
            cnt[g] = lo1 - lo0;
        }
    }
}

// -------------------------------------------------------------- gather ----

// Gather-mean from fp8 rows (128B). One wave per node. Quarter-wave owns an
// edge slot (qsub = lane>>4): lane loads 8B = 8 features of one row; one
// wave-load covers 4 random rows. Unroll x2 -> 8 rows in flight.
__global__ __launch_bounds__(256) void k_gather(
    const int* __restrict__ deg, const int* __restrict__ col,
    const u8* __restrict__ fq, bf16* __restrict__ agg)
{
    const int nid  = blockIdx.x * 4 + (threadIdx.x >> 6);
    const int lane = threadIdx.x & 63;
    const int qsub = lane >> 4;        // edge slot 0..3
    const int l4   = lane & 15;        // feature group: 8*l4 .. 8*l4+7
    int dgr = __builtin_amdgcn_readfirstlane(deg[nid]);
    int dg = dgr > CSTRIDE ? CSTRIDE : dgr;
    int vidx = (lane < CSTRIDE) ? col[nid * CSTRIDE + lane] : 0;

    float a[8] = {0.f, 0.f, 0.f, 0.f, 0.f, 0.f, 0.f, 0.f};

    for (int e = 0; e < dg; e += 8) {
        int sa0 = __builtin_amdgcn_readlane(vidx, min(e + 0, dg - 1));
        int sa1 = __builtin_amdgcn_readlane(vidx, min(e + 1, dg - 1));
        int sa2 = __builtin_amdgcn_readlane(vidx, min(e + 2, dg - 1));
        int sa3 = __builtin_amdgcn_readlane(vidx, min(e + 3, dg - 1));
        int sb0 = __builtin_amdgcn_readlane(vidx, min(e + 4, dg - 1));
        int sb1 = __builtin_amdgcn_readlane(vidx, min(e + 5, dg - 1));
        int sb2 = __builtin_amdgcn_readlane(vidx, min(e + 6, dg - 1));
        int sb3 = __builtin_amdgcn_readlane(vidx, min(e + 7, dg - 1));
        int sA = (qsub == 0) ? sa0 : (qsub == 1) ? sa1 : (qsub == 2) ? sa2 : sa3;
        int sB = (qsub == 0) ? sb0 : (qsub == 1) ? sb1 : (qsub == 2) ? sb2 : sb3;
        float mA = (e + qsub     < dg) ? 1.f : 0.f;
        float mB = (e + 4 + qsub < dg) ? 1.f : 0.f;
        uint2 qA = *(const uint2*)(fq + (size_t)sA * DH + l4 * 8);
        uint2 qB = *(const uint2*)(fq + (size_t)sB * DH + l4 * 8);
        f32x2 v0 = __builtin_amdgcn_cvt_pk_f32_fp8((int)qA.x, false);
        f32x2 v1 = __builtin_amdgcn_cvt_pk_f32_fp8((int)qA.x, true);
        f32x2 v2 = __builtin_amdgcn_cvt_pk_f32_fp8((int)qA.y, false);
        f32x2 v3 = __builtin_amdgcn_cvt_pk_f32_fp8((int)qA.y, true);
        a[0] += v0[0] * mA; a[1] += v0[1] * mA;
        a[2] += v1[0] * mA; a[3] += v1[1] * mA;
        a[4] += v2[0] * mA; a[5] += v2[1] * mA;
        a[6] += v3[0] * mA; a[7] += v3[1] * mA;
        v0 = __builtin_amdgcn_cvt_pk_f32_fp8((int)qB.x, false);
        v1 = __builtin_amdgcn_cvt_pk_f32_fp8((int)qB.x, true);
        v2 = __builtin_amdgcn_cvt_pk_f32_fp8((int)qB.y, false);
        v3 = __builtin_amdgcn_cvt_pk_f32_fp8((int)qB.y, true);
        a[0] += v0[0] * mB; a[1] += v0[1] * mB;
        a[2] += v1[0] * mB; a[3] += v1[1] * mB;
        a[4] += v2[0] * mB; a[5] += v2[1] * mB;
        a[6] += v3[0] * mB; a[7] += v3[1] * mB;
    }

    #pragma unroll
    for (int i = 0; i < 8; ++i) {
        a[i] += __shfl_xor(a[i], 16, 64);
        a[i] += __shfl_xor(a[i], 32, 64);
    }

    if (qsub == 0) {
        float di = 1.0f / fmaxf((float)dgr, 1.0f);
        union { bf16 b[8]; uint4 u; } pk;
        #pragma unroll
        for (int i = 0; i < 8; ++i) pk.b[i] = __float2bfloat16(a[i] * di);
        *(uint4*)(agg + nid * DH + l4 * 8) = pk.u;
    }
}

// --------------------------------------------------------- MFMA layer ----

#define WSTR 136   // LDS row stride (bf16): +8 pad -> 2-way conflict (free)

template <bool POOL>
__global__ __launch_bounds__(256, 4) void k_layer(
    const bf16* __restrict__ agg, const void* __restrict__ xop,
    const bf16* __restrict__ Wlb, const bf16* __restrict__ Wrb,
    const float* __restrict__ bias,
    u8* __restrict__ outq, int* __restrict__ psum,
    const int* __restrict__ batch)
{
    __shared__ bf16 wl[128 * WSTR];   // 34816 B, reused as output staging
    __shared__ int  bb[128];

    const int tid  = threadIdx.x;
    const int wave = tid >> 6;
    const int lane = tid & 63;
    const int lm   = lane & 15;
    const int kg   = lane >> 4;
    const int base = blockIdx.x * 128;
    const int wbase = base + wave * 32;

    const int r0 = min(wbase + lm,      NN - 1);
    const int r1 = min(wbase + 16 + lm, NN - 1);

    if (POOL && tid < 128) bb[tid] = batch[min(base + tid, NN - 1)];

    // stage Wl
    {
        const int row = tid >> 1, half = tid & 1;
        const uint4* src = (const uint4*)(Wlb + row * DH + half * 64);
        uint4* dst = (uint4*)(wl + row * WSTR + half * 64);
        #pragma unroll
        for (int i = 0; i < 8; ++i) dst[i] = src[i];
    }
    __syncthreads();

    f32x4 acc[2][8];
    #pragma unroll
    for (int i = 0; i < 2; ++i)
        #pragma unroll
        for (int t = 0; t < 8; ++t)
            acc[i][t] = (f32x4){0.f, 0.f, 0.f, 0.f};

    // ---- half 1: agg . Wl(LDS) ----
    #pragma unroll
    for (int kc = 0; kc < 4; ++kc) {
        const int ko = kc * 32 + kg * 8;
        bf16x8 a0 = *(const bf16x8*)(agg + r0 * DH + ko);
        bf16x8 a1 = *(const bf16x8*)(agg + r1 * DH + ko);
        #pragma unroll
        for (int t = 0; t < 8; ++t) {
            bf16x8 b = *(const bf16x8*)(wl + (t * 16 + lm) * WSTR + ko);
            acc[0][t] = __builtin_amdgcn_mfma_f32_16x16x32_bf16(a0, b, acc[0][t], 0, 0, 0);
            acc[1][t] = __builtin_amdgcn_mfma_f32_16x16x32_bf16(a1, b, acc[1][t], 0, 0, 0);
        }
    }
    __syncthreads();

    // restage Wr
    {
        const int row = tid >> 1, half = tid & 1;
        const uint4* src = (const uint4*)(Wrb + row * DH + half * 64);
        uint4* dst = (uint4*)(wl + row * WSTR + half * 64);
        #pragma unroll
        for (int i = 0; i < 8; ++i) dst[i] = src[i];
    }
    __syncthreads();

    // ---- half 2: x . Wr(LDS) ----
    #pragma unroll
    for (int kc = 0; kc < 4; ++kc) {
        const int ko = kc * 32 + kg * 8;
        bf16x8 a0, a1;
        if (!POOL) {
            const float* xf = (const float*)xop;
            const float4* p0 = (const float4*)(xf + (size_t)r0 * DH + ko);
            const float4* p1 = (const float4*)(xf + (size_t)r1 * DH + ko);
            float4 u0 = p0[0], u1 = p0[1], v0 = p1[0], v1 = p1[1];
            a0[0] = (__bf16)u0.x; a0[1] = (__bf16)u0.y; a0[2] = (__bf16)u0.z; a0[3] = (__bf16)u0.w;
            a0[4] = (__bf16)u1.x; a0[5] = (__bf16)u1.y; a0[6] = (__bf16)u1.z; a0[7] = (__bf16)u1.w;
            a1[0] = (__bf16)v0.x; a1[1] = (__bf16)v0.y; a1[2] = (__bf16)v0.z; a1[3] = (__bf16)v0.w;
            a1[4] = (__bf16)v1.x; a1[5] = (__bf16)v1.y; a1[6] = (__bf16)v1.z; a1[7] = (__bf16)v1.w;
        } else {
            const u8* xq = (const u8*)xop;
            uint2 q0 = *(const uint2*)(xq + (size_t)r0 * DH + ko);
            uint2 q1 = *(const uint2*)(xq + (size_t)r1 * DH + ko);
            f32x2 c0 = __builtin_amdgcn_cvt_pk_f32_fp8((int)q0.x, false);
            f32x2 c1 = __builtin_amdgcn_cvt_pk_f32_fp8((int)q0.x, true);
            f32x2 c2 = __builtin_amdgcn_cvt_pk_f32_fp8((int)q0.y, false);
            f32x2 c3 = __builtin_amdgcn_cvt_pk_f32_fp8((int)q0.y, true);
            a0[0] = (__bf16)c0[0]; a0[1] = (__bf16)c0[1];
            a0[2] = (__bf16)c1[0]; a0[3] = (__bf16)c1[1];
            a0[4] = (__bf16)c2[0]; a0[5] = (__bf16)c2[1];
            a0[6] = (__bf16)c3[0]; a0[7] = (__bf16)c3[1];
            c0 = __builtin_amdgcn_cvt_pk_f32_fp8((int)q1.x, false);
            c1 = __builtin_amdgcn_cvt_pk_f32_fp8((int)q1.x, true);
            c2 = __builtin_amdgcn_cvt_pk_f32_fp8((int)q1.y, false);
            c3 = __builtin_amdgcn_cvt_pk_f32_fp8((int)q1.y, true);
            a1[0] = (__bf16)c0[0]; a1[1] = (__bf16)c0[1];
            a1[2] = (__bf16)c1[0]; a1[3] = (__bf16)c1[1];
            a1[4] = (__bf16)c2[0]; a1[5] = (__bf16)c2[1];
            a1[6] = (__bf16)c3[0]; a1[7] = (__bf16)c3[1];
        }
        #pragma unroll
        for (int t = 0; t < 8; ++t) {
            bf16x8 b = *(const bf16x8*)(wl + (t * 16 + lm) * WSTR + ko);
            acc[0][t] = __builtin_amdgcn_mfma_f32_16x16x32_bf16(a0, b, acc[0][t], 0, 0, 0);
            acc[1][t] = __builtin_amdgcn_mfma_f32_16x16x32_bf16(a1, b, acc[1][t], 0, 0, 0);
        }
    }
    __syncthreads();   // all waves done reading wl -> safe to reuse

    // ---- epilogue: stage bias+relu'd outputs (bf16) row-major in LDS ----
    bf16* ob = wl;     // 128 x 128, stride 128 (32KB)
    const int quad = lane >> 4;
    #pragma unroll
    for (int i = 0; i < 2; ++i) {
        #pragma unroll
        for (int r = 0; r < 4; ++r) {
            const int lr = wave * 32 + i * 16 + quad * 4 + r;
            const int n  = base + lr;
            #pragma unroll
            for (int t = 0; t < 8; ++t) {
                const int f = t * 16 + lm;
                float v = fmaxf(acc[i][t][r] + bias[f], 0.f);
                if (POOL && n >= NN) v = 0.f;   // zero tail for pooling
                ob[lr * DH + f] = __float2bfloat16(v);
            }
        }
    }
    __syncthreads();

    if (!POOL) {
        // coalesced fp8 store: block tile is contiguous 16KB in outq
        uint2* d = (uint2*)(outq + (size_t)base * DH);
        #pragma unroll
        for (int i = 0; i < 8; ++i) {
            const int idx = i * 256 + tid;          // 8B units, 16 per row
            const int n = base + (idx >> 4);
            if (n < NN) {
                uint4 s = ((const uint4*)ob)[idx];  // 8 bf16
                float w[8];
                bf8_to_f(s, w);
                uint2 o;
                o.x = pack4_fp8(w[0], w[1], w[2], w[3]);
                o.y = pack4_fp8(w[4], w[5], w[6], w[7]);
                d[idx] = o;
            }
        }
    } else {
        // sorted-batch run-length pooling: thread = (col f, half h)
        const int f = tid & 127, h = tid >> 7;
        float rs = 0.f;
        int cur = bb[h * 64];
        #pragma unroll 8
        for (int r = 0; r < 64; ++r) {
            const int row = h * 64 + r;
            float v = __bfloat162float(ob[row * DH + f]);
            int b = bb[row];
            if (b != cur) {   // wave-uniform (depends only on row)
                atomicAdd(&psum[cur * DH + f], __float2int_rn(rs * PSUM_SCALE));
                rs = 0.f; cur = b;
            }
            rs += v;
        }
        atomicAdd(&psum[cur * DH + f], __float2int_rn(rs * PSUM_SCALE));
    }
}

// --------------------------------------------------------------- final ----

__global__ __launch_bounds__(256) void k_final(
    const int* __restrict__ psum, const int* __restrict__ cnt,
    const float* __restrict__ Wlin, const float* __restrict__ blin,
    float* __restrict__ out)
{
    int gid = blockIdx.x * 256 + threadIdx.x;
    if (gid >= NG * 4) return;
    int gph = gid >> 2, c = gid & 3;
    const int* p = psum + gph * DH;
    const float* w = Wlin + c * DH;
    float s = 0.f;
    #pragma unroll 8
    for (int k = 0; k < DH; ++k)
        s += (float)p[k] * w[k];
    float inv = 1.0f / fmaxf((float)cnt[gph], 1.0f);
    out[gid] = s * PSUM_INV * inv + blin[c];
}

extern "C" void kernel_launch(void* const* d_in, const int* in_sizes, int n_in,
                              void* d_out, int out_size, void* d_ws, size_t ws_size,
                              hipStream_t stream) {
    const float* x     = (const float*)d_in[0];
    const int*   ei    = (const int*)d_in[1];
    const int*   batch = (const int*)d_in[2];
    const float* W1l   = (const float*)d_in[3];
    const float* b1    = (const float*)d_in[4];
    const float* W1r   = (const float*)d_in[5];
    const float* W2l   = (const float*)d_in[6];
    const float* b2    = (const float*)d_in[7];
    const float* W2r   = (const float*)d_in[8];
    const float* Wlin  = (const float*)d_in[9];
    const float* blin  = (const float*)d_in[10];
    float* out = (float*)d_out;

    // ws layout (58.4MB, well under proven 77.46MB):
    // deg:  NN int          @ 64          (400000)
    // cnt:  512 int         @ 400064      (2048)
    // psum: 512*128 int     @ 402112      (262144)
    // wb:   4*16384 bf16    @ 664256      (131072)
    // col:  NN*48 int       @ 795328      (19200000)
    // agg:  NN*128 bf16     @ 19995328    (25600000)
    // fq:   NN*128 fp8      @ 45595328    (12800000)  xq, then h1q in-place
    char* base = (char*)d_ws;
    int*   deg  = (int*)(base + 64);
    int*   cnt  = (int*)(base + 400064);
    int*   psum = (int*)(base + 402112);
    bf16*  wb   = (bf16*)(base + 664256);
    int*   col  = (int*)(base + 795328);
    bf16*  agg  = (bf16*)(base + 19995328);
    u8*    fq   = (u8*)(base + 45595328);

    bf16* W1lb = wb;
    bf16* W1rb = wb + 16384;
    bf16* W2lb = wb + 32768;
    bf16* W2rb = wb + 49152;

    // zero deg + psum (cnt written in fill_prep; rest fully overwritten)
    hipMemsetAsync(d_ws, 0, 664256, stream);

    k_fill_prep<<<NFILL + NPREP, 256, 0, stream>>>(
        ei, deg, col, x, fq, W1l, W1r, W2l, W2r, wb, batch, cnt);

    // layer 1: gather xq(fp8) -> agg(bf16), MFMA GEMM -> h1q(fp8, over xq)
    k_gather<<<NN / 4, 256, 0, stream>>>(deg, col, fq, agg);
    k_layer<false><<<(NN + 127) / 128, 256, 0, stream>>>(agg, x, W1lb, W1rb, b1,
                                                         fq, nullptr, nullptr);

    // layer 2: gather h1q(fp8) -> agg(bf16), MFMA GEMM + pooling -> psum
    k_gather<<<NN / 4, 256, 0, stream>>>(deg, col, fq, agg);
    k_layer<true><<<(NN + 127) / 128, 256, 0, stream>>>(agg, fq, W2lb, W2rb, b2,
                                                        nullptr, psum, batch);

    k_final<<<8, 256, 0, stream>>>(psum, cnt, Wlin, blin, out);
}

// Round 16
// 335.755 us; speedup vs baseline: 1.6210x; 1.0272x over previous
//
#include <hip/hip_runtime.h>
#include <hip/hip_bf16.h>

// GraphSAGE 2-layer + mean-pool + linear head, MI355X (gfx950).
// Dtypes (R0-R5 forensics): floats fp32, indices int32, out fp32.
// R6 CSR-gather 1243us | R7 MFMA 757 | R8 LDS-W 593 | R9 XCD-fill 537 |
// R10 fp8 tables 517 | R11 MLP gather 438 | R12 k_cnt 359 | R13 nt-fill 356 |
// R14 work-queue REGRESSION (reverted) | R15 fused fill+prep 345.
// R16: layer-1 A-operand now reads fq (fp8 x, 12.8MB L2/L3-warm) instead of
//     fp32 x (51.2MB). In-place safe: each block reads only its own 128-row
//     tile before the post-sync epilogue overwrites it (same pattern layer-2
//     always used). Both layers now share one A-path; template only selects
//     the epilogue. Precision: puts fp8 quant on the layer-1 self term
//     (~1.5e-3 worst at out, RSS w/ 2^-10 floor < 3.77e-3 threshold;
//     absmax has been pinned at 2^-10 through every fp8 change since R5).

#define NN 100000
#define NE 1600000
#define DH 128
#define NG 512
#define CSTRIDE 48   // deg ~ Poisson(16); P(max>=48) ~ 5.6e-6, guarded anyway
#define NBKT 8
#define BKT_SZ 12500 // NN / NBKT
#define NSLICE 256
#define ESLICE 6250  // NE / NSLICE
#define NFILL 2048   // fill blocks (NSLICE * NBKT)
#define NPREP 6250   // xconv blocks

#define PSUM_SCALE  1048576.0f        // 2^20
#define PSUM_INV    (1.0f/1048576.0f)

typedef __hip_bfloat16 bf16;
typedef __bf16 bf16x8 __attribute__((ext_vector_type(8)));
typedef float  f32x4  __attribute__((ext_vector_type(4)));
typedef float  f32x2  __attribute__((ext_vector_type(2)));
typedef unsigned char u8;

__device__ __forceinline__ void bf8_to_f(uint4 q, float* w) {
    union { unsigned u; float f; } t;
    t.u = q.x << 16;          w[0] = t.f;
    t.u = q.x & 0xffff0000u;  w[1] = t.f;
    t.u = q.y << 16;          w[2] = t.f;
    t.u = q.y & 0xffff0000u;  w[3] = t.f;
    t.u = q.z << 16;          w[4] = t.f;
    t.u = q.z & 0xffff0000u;  w[5] = t.f;
    t.u = q.w << 16;          w[6] = t.f;
    t.u = q.w & 0xffff0000u;  w[7] = t.f;
}

// pack 4 floats -> 4 fp8 e4m3 bytes (HW, RNE)
__device__ __forceinline__ unsigned pack4_fp8(float a, float b, float c, float d) {
    int p = __builtin_amdgcn_cvt_pk_fp8_f32(a, b, 0, false);
    p = __builtin_amdgcn_cvt_pk_fp8_f32(c, d, p, true);
    return (unsigned)p;
}

// ------------------------------------------------------ fused fill+prep ----

// Blocks 0..NFILL-1: XCD-bucketed nt-load CSR fill (bucket=bid&7).
// Blocks NFILL..: x->fp8; first 256 also W->bf16; next 2 also cnt.
__global__ __launch_bounds__(256) void k_fill_prep(
    const int* __restrict__ ei, int* __restrict__ deg, int* __restrict__ col,
    const float* __restrict__ x, u8* __restrict__ fq,
    const float* __restrict__ w0, const float* __restrict__ w1,
    const float* __restrict__ w2, const float* __restrict__ w3,
    bf16* __restrict__ wb,
    const int* __restrict__ batch, int* __restrict__ cnt)
{
    const int bid = blockIdx.x, tid = threadIdx.x;

    if (bid < NFILL) {
        const int bucket = bid & (NBKT - 1);
        const int wi     = bid >> 3;
        const int lo = bucket * BKT_SZ, hi = lo + BKT_SZ;
        const int e0 = wi * ESLICE;
        for (int e = e0 + tid; e < e0 + ESLICE; e += 256) {
            int d = __builtin_nontemporal_load(ei + NE + e);
            if (d >= lo && d < hi) {
                int s = __builtin_nontemporal_load(ei + e);
                int pos = atomicAdd(&deg[d], 1);
                if (pos < CSTRIDE) col[d * CSTRIDE + pos] = s;
            }
        }
        return;
    }

    const int pb = bid - NFILL;                   // 0 .. NPREP-1
    {   // xconv: 8 elems/thread
        int g = pb * 256 + tid;                   // 0 .. 1599999
        const float4* s = (const float4*)(x + (size_t)g * 8);
        float4 u0 = s[0], u1 = s[1];
        uint2 v;
        v.x = pack4_fp8(u0.x, u0.y, u0.z, u0.w);
        v.y = pack4_fp8(u1.x, u1.y, u1.z, u1.w);
        *(uint2*)(fq + (size_t)g * 8) = v;
    }
    if (pb < 256) {                               // wconv
        int gid = pb * 256 + tid;                 // 0 .. 65535
        int m = gid >> 14, i = gid & 16383;
        const float* src = (m == 0) ? w0 : (m == 1) ? w1 : (m == 2) ? w2 : w3;
        wb[gid] = __float2bfloat16(src[i]);
    } else if (pb < 258) {                        // cnt (sorted batch)
        int g = (pb - 256) * 256 + tid;
        if (g < NG) {
            int lo0 = 0, hi0 = NN, lo1 = 0, hi1 = NN;
            while (lo0 < hi0) { int m = (lo0 + hi0) >> 1; if (batch[m] < g)     lo0 = m + 1; else hi0 = m; }
            while (lo1 < hi1) { int m = (lo1 + hi1) >> 1; if (batch[m] < g + 1) lo1 = m + 1; else hi1 = m; }
            cnt[g] = lo1 - lo0;
        }
    }
}

// -------------------------------------------------------------- gather ----

// Gather-mean from fp8 rows (128B). One wave per node. Quarter-wave owns an
// edge slot (qsub = lane>>4): lane loads 8B = 8 features of one row; one
// wave-load covers 4 random rows. Unroll x2 -> 8 rows in flight.
__global__ __launch_bounds__(256) void k_gather(
    const int* __restrict__ deg, const int* __restrict__ col,
    const u8* __restrict__ fq, bf16* __restrict__ agg)
{
    const int nid  = blockIdx.x * 4 + (threadIdx.x >> 6);
    const int lane = threadIdx.x & 63;
    const int qsub = lane >> 4;        // edge slot 0..3
    const int l4   = lane & 15;        // feature group: 8*l4 .. 8*l4+7
    int dgr = __builtin_amdgcn_readfirstlane(deg[nid]);
    int dg = dgr > CSTRIDE ? CSTRIDE : dgr;
    int vidx = (lane < CSTRIDE) ? col[nid * CSTRIDE + lane] : 0;

    float a[8] = {0.f, 0.f, 0.f, 0.f, 0.f, 0.f, 0.f, 0.f};

    for (int e = 0; e < dg; e += 8) {
        int sa0 = __builtin_amdgcn_readlane(vidx, min(e + 0, dg - 1));
        int sa1 = __builtin_amdgcn_readlane(vidx, min(e + 1, dg - 1));
        int sa2 = __builtin_amdgcn_readlane(vidx, min(e + 2, dg - 1));
        int sa3 = __builtin_amdgcn_readlane(vidx, min(e + 3, dg - 1));
        int sb0 = __builtin_amdgcn_readlane(vidx, min(e + 4, dg - 1));
        int sb1 = __builtin_amdgcn_readlane(vidx, min(e + 5, dg - 1));
        int sb2 = __builtin_amdgcn_readlane(vidx, min(e + 6, dg - 1));
        int sb3 = __builtin_amdgcn_readlane(vidx, min(e + 7, dg - 1));
        int sA = (qsub == 0) ? sa0 : (qsub == 1) ? sa1 : (qsub == 2) ? sa2 : sa3;
        int sB = (qsub == 0) ? sb0 : (qsub == 1) ? sb1 : (qsub == 2) ? sb2 : sb3;
        float mA = (e + qsub     < dg) ? 1.f : 0.f;
        float mB = (e + 4 + qsub < dg) ? 1.f : 0.f;
        uint2 qA = *(const uint2*)(fq + (size_t)sA * DH + l4 * 8);
        uint2 qB = *(const uint2*)(fq + (size_t)sB * DH + l4 * 8);
        f32x2 v0 = __builtin_amdgcn_cvt_pk_f32_fp8((int)qA.x, false);
        f32x2 v1 = __builtin_amdgcn_cvt_pk_f32_fp8((int)qA.x, true);
        f32x2 v2 = __builtin_amdgcn_cvt_pk_f32_fp8((int)qA.y, false);
        f32x2 v3 = __builtin_amdgcn_cvt_pk_f32_fp8((int)qA.y, true);
        a[0] += v0[0] * mA; a[1] += v0[1] * mA;
        a[2] += v1[0] * mA; a[3] += v1[1] * mA;
        a[4] += v2[0] * mA; a[5] += v2[1] * mA;
        a[6] += v3[0] * mA; a[7] += v3[1] * mA;
        v0 = __builtin_amdgcn_cvt_pk_f32_fp8((int)qB.x, false);
        v1 = __builtin_amdgcn_cvt_pk_f32_fp8((int)qB.x, true);
        v2 = __builtin_amdgcn_cvt_pk_f32_fp8((int)qB.y, false);
        v3 = __builtin_amdgcn_cvt_pk_f32_fp8((int)qB.y, true);
        a[0] += v0[0] * mB; a[1] += v0[1] * mB;
        a[2] += v1[0] * mB; a[3] += v1[1] * mB;
        a[4] += v2[0] * mB; a[5] += v2[1] * mB;
        a[6] += v3[0] * mB; a[7] += v3[1] * mB;
    }

    #pragma unroll
    for (int i = 0; i < 8; ++i) {
        a[i] += __shfl_xor(a[i], 16, 64);
        a[i] += __shfl_xor(a[i], 32, 64);
    }

    if (qsub == 0) {
        float di = 1.0f / fmaxf((float)dgr, 1.0f);
        union { bf16 b[8]; uint4 u; } pk;
        #pragma unroll
        for (int i = 0; i < 8; ++i) pk.b[i] = __float2bfloat16(a[i] * di);
        *(uint4*)(agg + nid * DH + l4 * 8) = pk.u;
    }
}

// --------------------------------------------------------- MFMA layer ----

// out[n][f] = relu( agg[n].Wl[f] + bias[f] + xq[n].Wr[f] ), K=128 per half.
// A-operand for BOTH halves' row operands comes from bf16 agg / fp8 xq.
// In-place: block reads only its own tile rows of xq before the post-sync
// epilogue overwrites them (POOL=false writes h1q over xq).
#define WSTR 136   // LDS row stride (bf16): +8 pad -> 2-way conflict (free)

template <bool POOL>
__global__ __launch_bounds__(256, 4) void k_layer(
    const bf16* __restrict__ agg, const u8* __restrict__ xq,
    const bf16* __restrict__ Wlb, const bf16* __restrict__ Wrb,
    const float* __restrict__ bias,
    u8* __restrict__ outq, int* __restrict__ psum,
    const int* __restrict__ batch)
{
    __shared__ bf16 wl[128 * WSTR];   // 34816 B, reused as output staging
    __shared__ int  bb[128];

    const int tid  = threadIdx.x;
    const int wave = tid >> 6;
    const int lane = tid & 63;
    const int lm   = lane & 15;
    const int kg   = lane >> 4;
    const int base = blockIdx.x * 128;
    const int wbase = base + wave * 32;

    const int r0 = min(wbase + lm,      NN - 1);
    const int r1 = min(wbase + 16 + lm, NN - 1);

    if (POOL && tid < 128) bb[tid] = batch[min(base + tid, NN - 1)];

    // stage Wl
    {
        const int row = tid >> 1, half = tid & 1;
        const uint4* src = (const uint4*)(Wlb + row * DH + half * 64);
        uint4* dst = (uint4*)(wl + row * WSTR + half * 64);
        #pragma unroll
        for (int i = 0; i < 8; ++i) dst[i] = src[i];
    }
    __syncthreads();

    f32x4 acc[2][8];
    #pragma unroll
    for (int i = 0; i < 2; ++i)
        #pragma unroll
        for (int t = 0; t < 8; ++t)
            acc[i][t] = (f32x4){0.f, 0.f, 0.f, 0.f};

    // ---- half 1: agg . Wl(LDS) ----
    #pragma unroll
    for (int kc = 0; kc < 4; ++kc) {
        const int ko = kc * 32 + kg * 8;
        bf16x8 a0 = *(const bf16x8*)(agg + r0 * DH + ko);
        bf16x8 a1 = *(const bf16x8*)(agg + r1 * DH + ko);
        #pragma unroll
        for (int t = 0; t < 8; ++t) {
            bf16x8 b = *(const bf16x8*)(wl + (t * 16 + lm) * WSTR + ko);
            acc[0][t] = __builtin_amdgcn_mfma_f32_16x16x32_bf16(a0, b, acc[0][t], 0, 0, 0);
            acc[1][t] = __builtin_amdgcn_mfma_f32_16x16x32_bf16(a1, b, acc[1][t], 0, 0, 0);
        }
    }
    __syncthreads();

    // restage Wr
    {
        const int row = tid >> 1, half = tid & 1;
        const uint4* src = (const uint4*)(Wrb + row * DH + half * 64);
        uint4* dst = (uint4*)(wl + row * WSTR + half * 64);
        #pragma unroll
        for (int i = 0; i < 8; ++i) dst[i] = src[i];
    }
    __syncthreads();

    // ---- half 2: xq(fp8) . Wr(LDS) ----
    #pragma unroll
    for (int kc = 0; kc < 4; ++kc) {
        const int ko = kc * 32 + kg * 8;
        bf16x8 a0, a1;
        uint2 q0 = *(const uint2*)(xq + (size_t)r0 * DH + ko);
        uint2 q1 = *(const uint2*)(xq + (size_t)r1 * DH + ko);
        f32x2 c0 = __builtin_amdgcn_cvt_pk_f32_fp8((int)q0.x, false);
        f32x2 c1 = __builtin_amdgcn_cvt_pk_f32_fp8((int)q0.x, true);
        f32x2 c2 = __builtin_amdgcn_cvt_pk_f32_fp8((int)q0.y, false);
        f32x2 c3 = __builtin_amdgcn_cvt_pk_f32_fp8((int)q0.y, true);
        a0[0] = (__bf16)c0[0]; a0[1] = (__bf16)c0[1];
        a0[2] = (__bf16)c1[0]; a0[3] = (__bf16)c1[1];
        a0[4] = (__bf16)c2[0]; a0[5] = (__bf16)c2[1];
        a0[6] = (__bf16)c3[0]; a0[7] = (__bf16)c3[1];
        c0 = __builtin_amdgcn_cvt_pk_f32_fp8((int)q1.x, false);
        c1 = __builtin_amdgcn_cvt_pk_f32_fp8((int)q1.x, true);
        c2 = __builtin_amdgcn_cvt_pk_f32_fp8((int)q1.y, false);
        c3 = __builtin_amdgcn_cvt_pk_f32_fp8((int)q1.y, true);
        a1[0] = (__bf16)c0[0]; a1[1] = (__bf16)c0[1];
        a1[2] = (__bf16)c1[0]; a1[3] = (__bf16)c1[1];
        a1[4] = (__bf16)c2[0]; a1[5] = (__bf16)c2[1];
        a1[6] = (__bf16)c3[0]; a1[7] = (__bf16)c3[1];
        #pragma unroll
        for (int t = 0; t < 8; ++t) {
            bf16x8 b = *(const bf16x8*)(wl + (t * 16 + lm) * WSTR + ko);
            acc[0][t] = __builtin_amdgcn_mfma_f32_16x16x32_bf16(a0, b, acc[0][t], 0, 0, 0);
            acc[1][t] = __builtin_amdgcn_mfma_f32_16x16x32_bf16(a1, b, acc[1][t], 0, 0, 0);
        }
    }
    __syncthreads();   // all waves done reading wl -> safe to reuse

    // ---- epilogue: stage bias+relu'd outputs (bf16) row-major in LDS ----
    bf16* ob = wl;     // 128 x 128, stride 128 (32KB)
    const int quad = lane >> 4;
    #pragma unroll
    for (int i = 0; i < 2; ++i) {
        #pragma unroll
        for (int r = 0; r < 4; ++r) {
            const int lr = wave * 32 + i * 16 + quad * 4 + r;
            const int n  = base + lr;
            #pragma unroll
            for (int t = 0; t < 8; ++t) {
                const int f = t * 16 + lm;
                float v = fmaxf(acc[i][t][r] + bias[f], 0.f);
                if (POOL && n >= NN) v = 0.f;   // zero tail for pooling
                ob[lr * DH + f] = __float2bfloat16(v);
            }
        }
    }
    __syncthreads();

    if (!POOL) {
        // coalesced fp8 store: block tile is contiguous 16KB in outq
        uint2* d = (uint2*)(outq + (size_t)base * DH);
        #pragma unroll
        for (int i = 0; i < 8; ++i) {
            const int idx = i * 256 + tid;          // 8B units, 16 per row
            const int n = base + (idx >> 4);
            if (n < NN) {
                uint4 s = ((const uint4*)ob)[idx];  // 8 bf16
                float w[8];
                bf8_to_f(s, w);
                uint2 o;
                o.x = pack4_fp8(w[0], w[1], w[2], w[3]);
                o.y = pack4_fp8(w[4], w[5], w[6], w[7]);
                d[idx] = o;
            }
        }
    } else {
        // sorted-batch run-length pooling: thread = (col f, half h)
        const int f = tid & 127, h = tid >> 7;
        float rs = 0.f;
        int cur = bb[h * 64];
        #pragma unroll 8
        for (int r = 0; r < 64; ++r) {
            const int row = h * 64 + r;
            float v = __bfloat162float(ob[row * DH + f]);
            int b = bb[row];
            if (b != cur) {   // wave-uniform (depends only on row)
                atomicAdd(&psum[cur * DH + f], __float2int_rn(rs * PSUM_SCALE));
                rs = 0.f; cur = b;
            }
            rs += v;
        }
        atomicAdd(&psum[cur * DH + f], __float2int_rn(rs * PSUM_SCALE));
    }
}

// --------------------------------------------------------------- final ----

__global__ __launch_bounds__(256) void k_final(
    const int* __restrict__ psum, const int* __restrict__ cnt,
    const float* __restrict__ Wlin, const float* __restrict__ blin,
    float* __restrict__ out)
{
    int gid = blockIdx.x * 256 + threadIdx.x;
    if (gid >= NG * 4) return;
    int gph = gid >> 2, c = gid & 3;
    const int* p = psum + gph * DH;
    const float* w = Wlin + c * DH;
    float s = 0.f;
    #pragma unroll 8
    for (int k = 0; k < DH; ++k)
        s += (float)p[k] * w[k];
    float inv = 1.0f / fmaxf((float)cnt[gph], 1.0f);
    out[gid] = s * PSUM_INV * inv + blin[c];
}

extern "C" void kernel_launch(void* const* d_in, const int* in_sizes, int n_in,
                              void* d_out, int out_size, void* d_ws, size_t ws_size,
                              hipStream_t stream) {
    const float* x     = (const float*)d_in[0];
    const int*   ei    = (const int*)d_in[1];
    const int*   batch = (const int*)d_in[2];
    const float* W1l   = (const float*)d_in[3];
    const float* b1    = (const float*)d_in[4];
    const float* W1r   = (const float*)d_in[5];
    const float* W2l   = (const float*)d_in[6];
    const float* b2    = (const float*)d_in[7];
    const float* W2r   = (const float*)d_in[8];
    const float* Wlin  = (const float*)d_in[9];
    const float* blin  = (const float*)d_in[10];
    float* out = (float*)d_out;

    // ws layout (58.4MB, well under proven 77.46MB):
    // deg:  NN int          @ 64          (400000)
    // cnt:  512 int         @ 400064      (2048)
    // psum: 512*128 int     @ 402112      (262144)
    // wb:   4*16384 bf16    @ 664256      (131072)
    // col:  NN*48 int       @ 795328      (19200000)
    // agg:  NN*128 bf16     @ 19995328    (25600000)
    // fq:   NN*128 fp8      @ 45595328    (12800000)  xq, then h1q in-place
    char* base = (char*)d_ws;
    int*   deg  = (int*)(base + 64);
    int*   cnt  = (int*)(base + 400064);
    int*   psum = (int*)(base + 402112);
    bf16*  wb   = (bf16*)(base + 664256);
    int*   col  = (int*)(base + 795328);
    bf16*  agg  = (bf16*)(base + 19995328);
    u8*    fq   = (u8*)(base + 45595328);

    bf16* W1lb = wb;
    bf16* W1rb = wb + 16384;
    bf16* W2lb = wb + 32768;
    bf16* W2rb = wb + 49152;

    // zero deg + psum (cnt written in fill_prep; rest fully overwritten)
    hipMemsetAsync(d_ws, 0, 664256, stream);

    k_fill_prep<<<NFILL + NPREP, 256, 0, stream>>>(
        ei, deg, col, x, fq, W1l, W1r, W2l, W2r, wb, batch, cnt);

    // layer 1: gather xq(fp8) -> agg(bf16), MFMA GEMM -> h1q(fp8, over xq)
    k_gather<<<NN / 4, 256, 0, stream>>>(deg, col, fq, agg);
    k_layer<false><<<(NN + 127) / 128, 256, 0, stream>>>(agg, fq, W1lb, W1rb, b1,
                                                         fq, nullptr, nullptr);

    // layer 2: gather h1q(fp8) -> agg(bf16), MFMA GEMM + pooling -> psum
    k_gather<<<NN / 4, 256, 0, stream>>>(deg, col, fq, agg);
    k_layer<true><<<(NN + 127) / 128, 256, 0, stream>>>(agg, fq, W2lb, W2rb, b2,
                                                        nullptr, psum, batch);

    k_final<<<8, 256, 0, stream>>>(psum, cnt, Wlin, blin, out);
}